// Round 11
// baseline (42.689 us; speedup 1.0000x reference)
//
#include <hip/hip_runtime.h>
#include <math.h>

#define U 128
#define NIT 12   // fixed Picard iterations per layer (even); ρ≲0.5 measured across
                 // NIT∈{16,20,48} (absmax pinned at bf16-z quant floor 2e-3)

typedef __attribute__((ext_vector_type(8))) short bf16x8;
typedef __attribute__((ext_vector_type(4))) float f32x4;
typedef __attribute__((ext_vector_type(4))) unsigned int u32x4;

__device__ inline unsigned int pack2(float a, float b) {
    // low short = bf16(a) (truncated), high short = bf16(b)
    return (__float_as_uint(a) >> 16) | (__float_as_uint(b) & 0xFFFF0000u);
}
__device__ inline float lo_of(float a) {
    return a - __uint_as_float(__float_as_uint(a) & 0xFFFF0000u);
}
__device__ inline unsigned int packrn(float a, float b) {
    // RTNE pack (v_cvt_pk_bf16_f32): low = bf16_rn(a), high = bf16_rn(b)
    unsigned int r;
    asm("v_cvt_pk_bf16_f32 %0, %1, %2" : "=v"(r) : "v"(a), "v"(b));
    return r;
}
__device__ inline float fromhi(unsigned short h) {
    return __uint_as_float(((unsigned int)h) << 16);
}
__device__ inline float tanh_fast(float v) {
    float e = __expf(2.0f * v);
    return 1.0f - 2.0f / (e + 1.0f);
}
#define MFMA(A, B, C) __builtin_amdgcn_mfma_f32_16x16x32_bf16(A, B, C, 0, 0, 0)

// in-register f32 -> (trunc-bf16 hi, bf16 lo) split of 8 values
#define SPLIT8(P4, Q4, H, LO)                                              \
{   u32x4 h_, l_;                                                          \
    h_[0] = pack2(P4.x, P4.y); h_[1] = pack2(P4.z, P4.w);                  \
    h_[2] = pack2(Q4.x, Q4.y); h_[3] = pack2(Q4.z, Q4.w);                  \
    l_[0] = pack2(lo_of(P4.x), lo_of(P4.y));                               \
    l_[1] = pack2(lo_of(P4.z), lo_of(P4.w));                               \
    l_[2] = pack2(lo_of(Q4.x), lo_of(Q4.y));                               \
    l_[3] = pack2(lo_of(Q4.z), lo_of(Q4.w));                               \
    H  = __builtin_bit_cast(bf16x8, h_);                                   \
    LO = __builtin_bit_cast(bf16x8, l_); }

// ---------------------------------------------------------------------------
// k_gemm_in: zA = X @ Wi^T + bi (f32 out). UNCHANGED from R10.
// ---------------------------------------------------------------------------
__global__ __launch_bounds__(512) void k_gemm_in(
        const float* __restrict__ X, const float* __restrict__ Wi,
        const float* __restrict__ bi, float* __restrict__ zA) {
    __shared__ f32x4 redS[4][64];
    const int tid  = threadIdx.x;
    const int w    = tid >> 6;
    const int lane = tid & 63;
    const int l15  = lane & 15;
    const int lq   = lane >> 4;
    const int slab = blockIdx.x & 127;
    const int ch   = blockIdx.x >> 7;
    const int ct   = w & 3;
    const int kh   = w >> 2;
    const int r0   = slab * 16;
    const int cb   = ch * 64 + ct * 16;
    const int colA = cb + l15;
    const int KD   = 784;

    const float* xp = &X[(long)(r0 + l15) * KD];
    const float* wp = &Wi[(long)colA * KD];

    f32x4 a0 = {0.f, 0.f, 0.f, 0.f};
    f32x4 a1 = {0.f, 0.f, 0.f, 0.f};
    f32x4 a2 = {0.f, 0.f, 0.f, 0.f};
    if (kh == 0) {
        float4 b4 = *(const float4*)&bi[cb + lq * 4];
        a0[0] = b4.x; a0[1] = b4.y; a0[2] = b4.z; a0[3] = b4.w;
    }

    const int kbase = kh ? 384 : 0;
    #pragma unroll 6
    for (int c = 0; c < 12; ++c) {
        const int k = kbase + c * 32 + lq * 8;
        float4 xa = *(const float4*)&xp[k];
        float4 xb = *(const float4*)&xp[k + 4];
        float4 wa = *(const float4*)&wp[k];
        float4 wb = *(const float4*)&wp[k + 4];
        bf16x8 ah, al, bh, bl;
        SPLIT8(xa, xb, ah, al)
        SPLIT8(wa, wb, bh, bl)
        a0 = MFMA(bh, ah, a0);     // Wh . xh
        a1 = MFMA(bh, al, a1);     // Wh . xl
        a2 = MFMA(bl, ah, a2);     // Wl . xh
    }
    if (kh) {   // tail k = 768..783 (valid lq<2)
        float4 z4 = make_float4(0.f, 0.f, 0.f, 0.f);
        float4 xa = z4, xb = z4, wa = z4, wb = z4;
        if (lq < 2) {
            const int k = 768 + lq * 8;
            xa = *(const float4*)&xp[k];
            xb = *(const float4*)&xp[k + 4];
            wa = *(const float4*)&wp[k];
            wb = *(const float4*)&wp[k + 4];
        }
        bf16x8 ah, al, bh, bl;
        SPLIT8(xa, xb, ah, al)
        SPLIT8(wa, wb, bh, bl)
        a0 = MFMA(bh, ah, a0);
        a1 = MFMA(bh, al, a1);
        a2 = MFMA(bl, ah, a2);
    }

    f32x4 r;
    #pragma unroll
    for (int i = 0; i < 4; ++i) r[i] = a0[i] + a1[i] + a2[i];

    if (kh) redS[ct][lane] = r;
    __syncthreads();
    if (!kh) {
        f32x4 o = redS[ct][lane];
        float4 st;
        st.x = r[0] + o[0]; st.y = r[1] + o[1];
        st.z = r[2] + o[2]; st.w = r[3] + o[3];
        *(float4*)&zA[(long)(r0 + l15) * U + cb + lq * 4] = st;
    }
}

// ---------------------------------------------------------------------------
// k_picard: Picard layers + MFMA output GEMM + softmax. UNCHANGED from R10.
// ---------------------------------------------------------------------------
__global__ __launch_bounds__(256) void k_picard(
        const float* __restrict__ zA, const float* __restrict__ Wb,
        const float* __restrict__ Wo, const float* __restrict__ bo,
        float* __restrict__ Out, int L) {
    __shared__ unsigned short zhS[2][16 * U];   // 2 x 4 KB (double-buffered)

    const int tid  = threadIdx.x;
    const int w    = tid >> 6;          // 0..3
    const int lane = tid & 63;
    const int l15  = lane & 15;
    const int lq   = lane >> 4;
    const int r0   = blockIdx.x * 16;

    // x (z-lin): lane l15 = batch row; regs: ct0 cols 32w+4lq..+3, ct1 +16
    float xf[8], zr[8];
    {
        const float* zrow = &zA[(long)(r0 + l15) * U + w * 32 + lq * 4];
        float4 x40 = *(const float4*)&zrow[0];
        float4 x41 = *(const float4*)&zrow[16];
        xf[0] = x40.x; xf[1] = x40.y; xf[2] = x40.z; xf[3] = x40.w;
        xf[4] = x41.x; xf[5] = x41.y; xf[6] = x41.z; xf[7] = x41.w;
    }

    const int swz = (l15 & 7) << 4;
    int offA[4];
    #pragma unroll
    for (int ks = 0; ks < 4; ++ks)
        offA[ks] = l15 * 256 + ((64 * ks + 16 * lq) ^ swz);
    const int offW0 = l15 * 256 + (((64 * w + 8 * lq)) ^ swz);        // ct0
    const int offW1 = l15 * 256 + (((64 * w + 32 + 8 * lq)) ^ swz);   // ct1

    char* zhB = (char*)&zhS[0][0];

    for (int l = 0; l < L; ++l) {
        // layer weights for both col-tiles: f32 -> 3-term split in registers
        bf16x8 whf[2][4], wlf[2][4];
        #pragma unroll
        for (int ct = 0; ct < 2; ++ct) {
            const int colA = w * 32 + ct * 16 + l15;
            const float* wrow = &Wb[((long)l * U + colA) * U];
            #pragma unroll
            for (int ks = 0; ks < 4; ++ks) {
                const int k = ks * 32 + lq * 8;
                float4 p = *(const float4*)&wrow[k];
                float4 q = *(const float4*)&wrow[k + 4];
                SPLIT8(p, q, whf[ct][ks], wlf[ct][ks])
            }
        }

        // z0 = tanh(x) -> buffer 0
        {
            #pragma unroll
            for (int i = 0; i < 8; ++i) zr[i] = tanh_fast(xf[i]);
            uint2 h0, h1;
            h0.x = packrn(zr[0], zr[1]); h0.y = packrn(zr[2], zr[3]);
            h1.x = packrn(zr[4], zr[5]); h1.y = packrn(zr[6], zr[7]);
            *(uint2*)(zhB + offW0) = h0;
            *(uint2*)(zhB + offW1) = h1;
        }
        __syncthreads();

        #pragma unroll 2
        for (int it = 0; it < NIT; ++it) {
            const int cur = it & 1;
            const int nxt = cur ^ 1;
            bf16x8 zhf[4];
            #pragma unroll
            for (int ks = 0; ks < 4; ++ks)
                zhf[ks] = *(const bf16x8*)(zhB + cur * 4096 + offA[ks]);

            // 8 independent chains (2 ct x {hi,lo} x 2 halves), depth 2
            f32x4 A0 = {xf[0], xf[1], xf[2], xf[3]};
            f32x4 Z4 = {0.f, 0.f, 0.f, 0.f};
            f32x4 A1 = Z4, A2 = Z4, A3 = Z4;
            f32x4 B0 = {xf[4], xf[5], xf[6], xf[7]};
            f32x4 B1 = Z4, B2 = Z4, B3 = Z4;
            A0 = MFMA(whf[0][0], zhf[0], A0);
            B0 = MFMA(whf[1][0], zhf[0], B0);
            A1 = MFMA(whf[0][2], zhf[2], A1);
            B1 = MFMA(whf[1][2], zhf[2], B1);
            A2 = MFMA(wlf[0][0], zhf[0], A2);
            B2 = MFMA(wlf[1][0], zhf[0], B2);
            A3 = MFMA(wlf[0][2], zhf[2], A3);
            B3 = MFMA(wlf[1][2], zhf[2], B3);
            A0 = MFMA(whf[0][1], zhf[1], A0);
            B0 = MFMA(whf[1][1], zhf[1], B0);
            A1 = MFMA(whf[0][3], zhf[3], A1);
            B1 = MFMA(whf[1][3], zhf[3], B1);
            A2 = MFMA(wlf[0][1], zhf[1], A2);
            B2 = MFMA(wlf[1][1], zhf[1], B2);
            A3 = MFMA(wlf[0][3], zhf[3], A3);
            B3 = MFMA(wlf[1][3], zhf[3], B3);

            #pragma unroll
            for (int i = 0; i < 4; ++i) {
                zr[i]     = tanh_fast(A0[i] + A1[i] + A2[i] + A3[i]);
                zr[4 + i] = tanh_fast(B0[i] + B1[i] + B2[i] + B3[i]);
            }
            uint2 h0, h1;
            h0.x = packrn(zr[0], zr[1]); h0.y = packrn(zr[2], zr[3]);
            h1.x = packrn(zr[4], zr[5]); h1.y = packrn(zr[6], zr[7]);
            *(uint2*)(zhB + nxt * 4096 + offW0) = h0;
            *(uint2*)(zhB + nxt * 4096 + offW1) = h1;
            __syncthreads();
        }
        #pragma unroll
        for (int i = 0; i < 8; ++i) xf[i] = zr[i];   // next layer input
    }
    // NIT even => final z in buffer 0

    // ---------------- Phase 3 (wave 0): out = softmax(z @ Wo^T + bo) -------
    if (w == 0) {
        // A-frag: Wo rows (classes, pad >=10 with zeros), 2-term split
        bf16x8 woh[4], wol[4];
        #pragma unroll
        for (int ks = 0; ks < 4; ++ks) {
            float4 p = make_float4(0.f, 0.f, 0.f, 0.f), q = p;
            if (l15 < 10) {
                const float* worow = &Wo[l15 * U + ks * 32 + lq * 8];
                p = *(const float4*)&worow[0];
                q = *(const float4*)&worow[4];
            }
            SPLIT8(p, q, woh[ks], wol[ks])
        }
        // B-frag: final z from buffer 0
        bf16x8 zf[4];
        #pragma unroll
        for (int ks = 0; ks < 4; ++ks)
            zf[ks] = *(const bf16x8*)(zhB + offA[ks]);

        f32x4 d0 = {0.f, 0.f, 0.f, 0.f};
        f32x4 d1 = d0;
        #pragma unroll
        for (int ks = 0; ks < 4; ++ks) {
            d0 = MFMA(woh[ks], zf[ks], d0);
            d1 = MFMA(wol[ks], zf[ks], d1);
        }
        // lane l15 = batch row, reg i -> class 4lq+i
        float lg[4];
        #pragma unroll
        for (int i = 0; i < 4; ++i) {
            const int c = 4 * lq + i;
            lg[i] = (c < 10) ? (d0[i] + d1[i] + bo[c]) : -1e30f;
        }
        float m = fmaxf(fmaxf(lg[0], lg[1]), fmaxf(lg[2], lg[3]));
        m = fmaxf(m, __shfl_xor(m, 16));
        m = fmaxf(m, __shfl_xor(m, 32));
        float e[4], s = 0.f;
        #pragma unroll
        for (int i = 0; i < 4; ++i) { e[i] = __expf(lg[i] - m); s += e[i]; }
        s += __shfl_xor(s, 16);
        s += __shfl_xor(s, 32);
        const float inv = 1.0f / s;
        #pragma unroll
        for (int i = 0; i < 4; ++i) {
            const int c = 4 * lq + i;
            if (c < 10) Out[(long)(r0 + l15) * 10 + c] = e[i] * inv;
        }
    }
}

// ---------------------------------------------------------------------------
// MEASUREMENT ROUND: k_gemm_in launched TWICE (idempotent -- identical args,
// second launch rewrites zA with identical values; deterministic).
// T_g = Total(this round) - 33.87us - dispatch overhead. Pre-committed fork:
//   Total ~55-60 -> k_gemm_in dominant -> rewrite it (LDS-staged X, pipeline)
//   Total ~38-42 -> k_picard dominant  -> split row-tiles across more blocks
// ---------------------------------------------------------------------------
extern "C" void kernel_launch(void* const* d_in, const int* in_sizes, int n_in,
                              void* d_out, int out_size, void* d_ws, size_t ws_size,
                              hipStream_t stream) {
    const float* x  = (const float*)d_in[0];   // [B,784]
    const float* Wi = (const float*)d_in[1];   // [128,784]
    const float* bi = (const float*)d_in[2];   // [128]
    const float* Wb = (const float*)d_in[3];   // [L,128,128]
    const float* Wo = (const float*)d_in[4];   // [10,128]
    const float* bo = (const float*)d_in[5];   // [10]
    float* out = (float*)d_out;

    const int DIN = 784;
    const int B   = in_sizes[0] / DIN;             // 2048
    const int L   = in_sizes[3] / (U * U);         // 2

    float* zA = (float*)d_ws;                      // [B,U] f32

    k_gemm_in<<<256, 512, 0, stream>>>(x, Wi, bi, zA);   // duplicate (timing probe)
    k_gemm_in<<<256, 512, 0, stream>>>(x, Wi, bi, zA);
    k_picard<<<B / 16, 256, 0, stream>>>(zA, Wb, Wo, bo, out, L);
}

// Round 12
// 32.559 us; speedup vs baseline: 1.3111x; 1.3111x over previous
//
#include <hip/hip_runtime.h>
#include <math.h>

#define U 128
#define NIT 10   // fixed Picard iters/layer (even); ρ≤0.57 (NIT-12 ≡ NIT-48 absmax)
                 // → iter err ≤ 0.57^10/2 ≈ 1.8e-3, under threshold headroom

typedef __attribute__((ext_vector_type(8))) short bf16x8;
typedef __attribute__((ext_vector_type(4))) float f32x4;
typedef __attribute__((ext_vector_type(4))) unsigned int u32x4;

__device__ inline unsigned int pack2(float a, float b) {
    // low short = bf16(a) (truncated), high short = bf16(b)
    return (__float_as_uint(a) >> 16) | (__float_as_uint(b) & 0xFFFF0000u);
}
__device__ inline float lo_of(float a) {
    return a - __uint_as_float(__float_as_uint(a) & 0xFFFF0000u);
}
__device__ inline unsigned int packrn(float a, float b) {
    // RTNE pack (v_cvt_pk_bf16_f32): low = bf16_rn(a), high = bf16_rn(b)
    unsigned int r;
    asm("v_cvt_pk_bf16_f32 %0, %1, %2" : "=v"(r) : "v"(a), "v"(b));
    return r;
}
__device__ inline float fromhi(unsigned short h) {
    return __uint_as_float(((unsigned int)h) << 16);
}
__device__ inline float tanh_fast(float v) {
    float e = __expf(2.0f * v);
    return 1.0f - 2.0f / (e + 1.0f);
}
#define MFMA(A, B, C) __builtin_amdgcn_mfma_f32_16x16x32_bf16(A, B, C, 0, 0, 0)

// in-register f32 -> (trunc-bf16 hi, bf16 lo) split of 8 values
#define SPLIT8(P4, Q4, H, LO)                                              \
{   u32x4 h_, l_;                                                          \
    h_[0] = pack2(P4.x, P4.y); h_[1] = pack2(P4.z, P4.w);                  \
    h_[2] = pack2(Q4.x, Q4.y); h_[3] = pack2(Q4.z, Q4.w);                  \
    l_[0] = pack2(lo_of(P4.x), lo_of(P4.y));                               \
    l_[1] = pack2(lo_of(P4.z), lo_of(P4.w));                               \
    l_[2] = pack2(lo_of(Q4.x), lo_of(Q4.y));                               \
    l_[3] = pack2(lo_of(Q4.z), lo_of(Q4.w));                               \
    H  = __builtin_bit_cast(bf16x8, h_);                                   \
    LO = __builtin_bit_cast(bf16x8, l_); }

// ---------------------------------------------------------------------------
// k_gemm_in v2: zA = X @ Wi^T + bi (f32), TLP-fixed.
// grid: 512 blocks = 128 slabs x 4 col-chunks (32 cols), 512 thr, VGPR<=128
// (launch_bounds(512,4)) -> 2 blocks/CU co-resident = 4 waves/SIMD: the 12
// dependent chunk-load groups of v1 (~700cy L3 latency each, 1-2 waves/SIMD)
// become 6 groups hidden 4-deep. Same-slab blocks share an XCD (bid%8
// invariant in ch) -> X slab L2-shared.
// wave w: ct = w&1 (16-col tile), kq = w>>1 (K quarter: kq<3 -> 6 chunks,
// kq=3 -> 6 chunks + 16-tail). Cross-K reduce via LDS (kq0 sums + stores).
// ---------------------------------------------------------------------------
__global__ __launch_bounds__(512, 4) void k_gemm_in(
        const float* __restrict__ X, const float* __restrict__ Wi,
        const float* __restrict__ bi, float* __restrict__ zA) {
    __shared__ f32x4 redS[6][64];     // 6 KB
    const int tid  = threadIdx.x;
    const int w    = tid >> 6;
    const int lane = tid & 63;
    const int l15  = lane & 15;
    const int lq   = lane >> 4;
    const int slab = blockIdx.x & 127;
    const int ch   = blockIdx.x >> 7;        // 0..3
    const int ct   = w & 1;
    const int kq   = w >> 1;                 // 0..3
    const int r0   = slab * 16;
    const int cb   = ch * 32 + ct * 16;
    const int colA = cb + l15;
    const int KD   = 784;

    const float* xp = &X[(long)(r0 + l15) * KD];
    const float* wp = &Wi[(long)colA * KD];

    f32x4 a0 = {0.f, 0.f, 0.f, 0.f};
    f32x4 a1 = {0.f, 0.f, 0.f, 0.f};
    f32x4 a2 = {0.f, 0.f, 0.f, 0.f};
    if (kq == 0) {
        float4 b4 = *(const float4*)&bi[cb + lq * 4];
        a0[0] = b4.x; a0[1] = b4.y; a0[2] = b4.z; a0[3] = b4.w;
    }

    const int kbase = kq * 192;
    #pragma unroll
    for (int c = 0; c < 6; ++c) {
        const int k = kbase + c * 32 + lq * 8;
        float4 xa = *(const float4*)&xp[k];
        float4 xb = *(const float4*)&xp[k + 4];
        float4 wa = *(const float4*)&wp[k];
        float4 wb = *(const float4*)&wp[k + 4];
        bf16x8 ah, al, bh, bl;
        SPLIT8(xa, xb, ah, al)
        SPLIT8(wa, wb, bh, bl)
        a0 = MFMA(bh, ah, a0);     // Wh . xh
        a1 = MFMA(bh, al, a1);     // Wh . xl
        a2 = MFMA(bl, ah, a2);     // Wl . xh
    }
    if (kq == 3) {   // tail k = 768..783 (valid lq<2)
        float4 z4 = make_float4(0.f, 0.f, 0.f, 0.f);
        float4 xa = z4, xb = z4, wa = z4, wb = z4;
        if (lq < 2) {
            const int k = 768 + lq * 8;
            xa = *(const float4*)&xp[k];
            xb = *(const float4*)&xp[k + 4];
            wa = *(const float4*)&wp[k];
            wb = *(const float4*)&wp[k + 4];
        }
        bf16x8 ah, al, bh, bl;
        SPLIT8(xa, xb, ah, al)
        SPLIT8(wa, wb, bh, bl)
        a0 = MFMA(bh, ah, a0);
        a1 = MFMA(bh, al, a1);
        a2 = MFMA(bl, ah, a2);
    }

    f32x4 r;
    #pragma unroll
    for (int i = 0; i < 4; ++i) r[i] = a0[i] + a1[i] + a2[i];

    if (kq > 0) redS[(kq - 1) * 2 + ct][lane] = r;
    __syncthreads();
    if (kq == 0) {
        f32x4 s1 = redS[ct][lane];
        f32x4 s2 = redS[2 + ct][lane];
        f32x4 s3 = redS[4 + ct][lane];
        float4 st;
        st.x = r[0] + s1[0] + s2[0] + s3[0];
        st.y = r[1] + s1[1] + s2[1] + s3[1];
        st.z = r[2] + s1[2] + s2[2] + s3[2];
        st.w = r[3] + s1[3] + s2[3] + s3[3];
        *(float4*)&zA[(long)(r0 + l15) * U + cb + lq * 4] = st;
    }
}

// ---------------------------------------------------------------------------
// k_picard: Picard layers + MFMA output GEMM + softmax.
// grid: B/16 blocks, 256 threads (4 waves). Wave w owns cols 32w..32w+31.
// z in LDS as RTNE bf16 hi-only in-loop; final z written hi+lo (3-term
// phase 3) to remove the final-z quant floor. NIT=10.
// LDS z: byte(r,c) = r*256 + ((2c) ^ ((r&7)<<4))  XOR swizzle.
// ---------------------------------------------------------------------------
__global__ __launch_bounds__(256) void k_picard(
        const float* __restrict__ zA, const float* __restrict__ Wb,
        const float* __restrict__ Wo, const float* __restrict__ bo,
        float* __restrict__ Out, int L) {
    __shared__ unsigned short zhS[2][16 * U];   // 2 x 4 KB (dbuf; buf1 = z_lo at end)

    const int tid  = threadIdx.x;
    const int w    = tid >> 6;          // 0..3
    const int lane = tid & 63;
    const int l15  = lane & 15;
    const int lq   = lane >> 4;
    const int r0   = blockIdx.x * 16;

    // x (z-lin): lane l15 = batch row; regs: ct0 cols 32w+4lq..+3, ct1 +16
    float xf[8], zr[8];
    {
        const float* zrow = &zA[(long)(r0 + l15) * U + w * 32 + lq * 4];
        float4 x40 = *(const float4*)&zrow[0];
        float4 x41 = *(const float4*)&zrow[16];
        xf[0] = x40.x; xf[1] = x40.y; xf[2] = x40.z; xf[3] = x40.w;
        xf[4] = x41.x; xf[5] = x41.y; xf[6] = x41.z; xf[7] = x41.w;
    }

    const int swz = (l15 & 7) << 4;
    int offA[4];
    #pragma unroll
    for (int ks = 0; ks < 4; ++ks)
        offA[ks] = l15 * 256 + ((64 * ks + 16 * lq) ^ swz);
    const int offW0 = l15 * 256 + (((64 * w + 8 * lq)) ^ swz);        // ct0
    const int offW1 = l15 * 256 + (((64 * w + 32 + 8 * lq)) ^ swz);   // ct1

    char* zhB = (char*)&zhS[0][0];

    for (int l = 0; l < L; ++l) {
        // layer weights for both col-tiles: f32 -> 3-term split in registers
        bf16x8 whf[2][4], wlf[2][4];
        #pragma unroll
        for (int ct = 0; ct < 2; ++ct) {
            const int colA = w * 32 + ct * 16 + l15;
            const float* wrow = &Wb[((long)l * U + colA) * U];
            #pragma unroll
            for (int ks = 0; ks < 4; ++ks) {
                const int k = ks * 32 + lq * 8;
                float4 p = *(const float4*)&wrow[k];
                float4 q = *(const float4*)&wrow[k + 4];
                SPLIT8(p, q, whf[ct][ks], wlf[ct][ks])
            }
        }

        // z0 = tanh(x) -> buffer 0
        {
            #pragma unroll
            for (int i = 0; i < 8; ++i) zr[i] = tanh_fast(xf[i]);
            uint2 h0, h1;
            h0.x = packrn(zr[0], zr[1]); h0.y = packrn(zr[2], zr[3]);
            h1.x = packrn(zr[4], zr[5]); h1.y = packrn(zr[6], zr[7]);
            *(uint2*)(zhB + offW0) = h0;
            *(uint2*)(zhB + offW1) = h1;
        }
        __syncthreads();

        #pragma unroll 2
        for (int it = 0; it < NIT; ++it) {
            const int cur = it & 1;
            const int nxt = cur ^ 1;
            bf16x8 zhf[4];
            #pragma unroll
            for (int ks = 0; ks < 4; ++ks)
                zhf[ks] = *(const bf16x8*)(zhB + cur * 4096 + offA[ks]);

            // 8 independent chains (2 ct x {hi,lo} x 2 halves), depth 2
            f32x4 A0 = {xf[0], xf[1], xf[2], xf[3]};
            f32x4 Z4 = {0.f, 0.f, 0.f, 0.f};
            f32x4 A1 = Z4, A2 = Z4, A3 = Z4;
            f32x4 B0 = {xf[4], xf[5], xf[6], xf[7]};
            f32x4 B1 = Z4, B2 = Z4, B3 = Z4;
            A0 = MFMA(whf[0][0], zhf[0], A0);
            B0 = MFMA(whf[1][0], zhf[0], B0);
            A1 = MFMA(whf[0][2], zhf[2], A1);
            B1 = MFMA(whf[1][2], zhf[2], B1);
            A2 = MFMA(wlf[0][0], zhf[0], A2);
            B2 = MFMA(wlf[1][0], zhf[0], B2);
            A3 = MFMA(wlf[0][2], zhf[2], A3);
            B3 = MFMA(wlf[1][2], zhf[2], B3);
            A0 = MFMA(whf[0][1], zhf[1], A0);
            B0 = MFMA(whf[1][1], zhf[1], B0);
            A1 = MFMA(whf[0][3], zhf[3], A1);
            B1 = MFMA(whf[1][3], zhf[3], B1);
            A2 = MFMA(wlf[0][1], zhf[1], A2);
            B2 = MFMA(wlf[1][1], zhf[1], B2);
            A3 = MFMA(wlf[0][3], zhf[3], A3);
            B3 = MFMA(wlf[1][3], zhf[3], B3);

            #pragma unroll
            for (int i = 0; i < 4; ++i) {
                zr[i]     = tanh_fast(A0[i] + A1[i] + A2[i] + A3[i]);
                zr[4 + i] = tanh_fast(B0[i] + B1[i] + B2[i] + B3[i]);
            }
            uint2 h0, h1;
            h0.x = packrn(zr[0], zr[1]); h0.y = packrn(zr[2], zr[3]);
            h1.x = packrn(zr[4], zr[5]); h1.y = packrn(zr[6], zr[7]);
            *(uint2*)(zhB + nxt * 4096 + offW0) = h0;
            *(uint2*)(zhB + nxt * 4096 + offW1) = h1;
            __syncthreads();
        }
        #pragma unroll
        for (int i = 0; i < 8; ++i) xf[i] = zr[i];   // next layer input
    }
    // NIT even => final z hi in buffer 0. Write z_lo (residual vs stored hi)
    // to buffer 1 for the 3-term output GEMM.
    {
        uint2 l0, l1;
        l0.x = packrn(zr[0] - fromhi((unsigned short)(packrn(zr[0], zr[0]))),
                      zr[1] - fromhi((unsigned short)(packrn(zr[1], zr[1]))));
        l0.y = packrn(zr[2] - fromhi((unsigned short)(packrn(zr[2], zr[2]))),
                      zr[3] - fromhi((unsigned short)(packrn(zr[3], zr[3]))));
        l1.x = packrn(zr[4] - fromhi((unsigned short)(packrn(zr[4], zr[4]))),
                      zr[5] - fromhi((unsigned short)(packrn(zr[5], zr[5]))));
        l1.y = packrn(zr[6] - fromhi((unsigned short)(packrn(zr[6], zr[6]))),
                      zr[7] - fromhi((unsigned short)(packrn(zr[7], zr[7]))));
        *(uint2*)(zhB + 4096 + offW0) = l0;
        *(uint2*)(zhB + 4096 + offW1) = l1;
    }
    __syncthreads();

    // ---------------- Phase 3 (wave 0): out = softmax(z @ Wo^T + bo) -------
    if (w == 0) {
        // A-frag: Wo rows (classes, pad >=10 with zeros), 2-term split
        bf16x8 woh[4], wol[4];
        #pragma unroll
        for (int ks = 0; ks < 4; ++ks) {
            float4 p = make_float4(0.f, 0.f, 0.f, 0.f), q = p;
            if (l15 < 10) {
                const float* worow = &Wo[l15 * U + ks * 32 + lq * 8];
                p = *(const float4*)&worow[0];
                q = *(const float4*)&worow[4];
            }
            SPLIT8(p, q, woh[ks], wol[ks])
        }
        // B-frags: final z hi (buf0) + lo (buf1)
        bf16x8 zf[4], zl[4];
        #pragma unroll
        for (int ks = 0; ks < 4; ++ks) {
            zf[ks] = *(const bf16x8*)(zhB + offA[ks]);
            zl[ks] = *(const bf16x8*)(zhB + 4096 + offA[ks]);
        }

        f32x4 d0 = {0.f, 0.f, 0.f, 0.f};
        f32x4 d1 = d0, d2 = d0;
        #pragma unroll
        for (int ks = 0; ks < 4; ++ks) {
            d0 = MFMA(woh[ks], zf[ks], d0);
            d1 = MFMA(wol[ks], zf[ks], d1);
            d2 = MFMA(woh[ks], zl[ks], d2);
        }
        // lane l15 = batch row, reg i -> class 4lq+i
        float lg[4];
        #pragma unroll
        for (int i = 0; i < 4; ++i) {
            const int c = 4 * lq + i;
            lg[i] = (c < 10) ? (d0[i] + d1[i] + d2[i] + bo[c]) : -1e30f;
        }
        float m = fmaxf(fmaxf(lg[0], lg[1]), fmaxf(lg[2], lg[3]));
        m = fmaxf(m, __shfl_xor(m, 16));
        m = fmaxf(m, __shfl_xor(m, 32));
        float e[4], s = 0.f;
        #pragma unroll
        for (int i = 0; i < 4; ++i) { e[i] = __expf(lg[i] - m); s += e[i]; }
        s += __shfl_xor(s, 16);
        s += __shfl_xor(s, 32);
        const float inv = 1.0f / s;
        #pragma unroll
        for (int i = 0; i < 4; ++i) {
            const int c = 4 * lq + i;
            if (c < 10) Out[(long)(r0 + l15) * 10 + c] = e[i] * inv;
        }
    }
}

// ---------------------------------------------------------------------------
extern "C" void kernel_launch(void* const* d_in, const int* in_sizes, int n_in,
                              void* d_out, int out_size, void* d_ws, size_t ws_size,
                              hipStream_t stream) {
    const float* x  = (const float*)d_in[0];   // [B,784]
    const float* Wi = (const float*)d_in[1];   // [128,784]
    const float* bi = (const float*)d_in[2];   // [128]
    const float* Wb = (const float*)d_in[3];   // [L,128,128]
    const float* Wo = (const float*)d_in[4];   // [10,128]
    const float* bo = (const float*)d_in[5];   // [10]
    float* out = (float*)d_out;

    const int DIN = 784;
    const int B   = in_sizes[0] / DIN;             // 2048
    const int L   = in_sizes[3] / (U * U);         // 2

    float* zA = (float*)d_ws;                      // [B,U] f32

    k_gemm_in<<<512, 512, 0, stream>>>(x, Wi, bi, zA);
    k_picard<<<B / 16, 256, 0, stream>>>(zA, Wb, Wo, bo, out, L);
}